// Round 2
// baseline (49.740 us; speedup 1.0000x reference)
//
#include <hip/hip_runtime.h>

// SvmLoss N=8192, RANK_RATIO=1.0 -> out = rank_loss only.
// rank_loss = sum_{i,j} [time_i<time_j && status_i==1] * max(1+logit_j-logit_i,0)^2
//             / max(#maskpairs,1)
//
// Layout: lane owns column j (lj,tmj in VGPRs, no inner-loop LDS); i is a
// wave-uniform loop -> status[i]==1 is a SCALAR branch (skips ~half the
// iterations), logit[i]/st[i] are s_loads, pair count via ballot+popc (SALU).
// Single kernel: last-block-done pattern does the final deterministic reduce.

constexpr int N_   = 8192;
constexpr int BLK  = 256;
constexpr int NJB  = N_ / BLK;   // 32 j-blocks (one column per thread)
constexpr int NIC  = 32;         // i-chunks
constexpr int ICH  = N_ / NIC;   // 256 i per chunk
constexpr int GRID = NJB * NIC;  // 1024 blocks = 4/CU, 16 waves/CU

__global__ __launch_bounds__(BLK) void svm_fused(
        const float* __restrict__ logit,
        const float* __restrict__ st,      // [N][2] status,time
        float* __restrict__ psum,
        int*   __restrict__ pcnt,
        unsigned int* __restrict__ counter,
        float* __restrict__ out) {
    const int jb = blockIdx.x & (NJB - 1);
    const int ic = blockIdx.x / NJB;
    const int j  = jb * BLK + (int)threadIdx.x;

    const float lj  = logit[j];        // per-lane column data, registers
    const float tmj = st[2 * j + 1];

    const uint2* __restrict__ stu = (const uint2*)st;

    float sum = 0.0f;
    int   cnt = 0;                     // wave-uniform (ballot popcount)

    const int i0 = ic * ICH;
    #pragma unroll 4
    for (int k = 0; k < ICH; ++k) {
        const int   i  = i0 + k;
        const uint2 sv = stu[i];       // s_load_dwordx2: status,time bits
        const float li = logit[i];     // s_load (hoisted out of branch)
        if (sv.x == 0x3f800000u) {     // status==1.0f: UNIFORM scalar branch
            const float tmi = __uint_as_float(sv.y);
            const float t   = (1.0f - li) + lj;   // 1 + logit_j - logit_i
            const bool  m   = tmi < tmj;          // rank mask (counted)
            const bool  ok  = m && (t > 0.0f);    // contributes to sum
            const float hm  = ok ? t : 0.0f;
            sum = fmaf(hm, hm, sum);
            cnt += (int)__popcll(__ballot(m));    // SALU: s_bcnt1 + s_add
        }
    }

    // Wave reduce sum (cnt already wave-uniform)
    for (int off = 32; off > 0; off >>= 1)
        sum += __shfl_down(sum, off, 64);

    __shared__ float wsum[BLK / 64];
    __shared__ int   wcnt[BLK / 64];
    __shared__ bool  last;
    const int lane = threadIdx.x & 63;
    const int wid  = threadIdx.x >> 6;
    if (lane == 0) { wsum[wid] = sum; wcnt[wid] = cnt; }
    __syncthreads();
    if (threadIdx.x == 0) {
        float s = wsum[0] + wsum[1] + wsum[2] + wsum[3];
        int   c = wcnt[0] + wcnt[1] + wcnt[2] + wcnt[3];
        psum[blockIdx.x] = s;
        pcnt[blockIdx.x] = c;
        __threadfence();                       // release partials device-wide
        unsigned int old = atomicAdd(counter, 1u);
        last = (old == GRID - 1);
    }
    __syncthreads();

    if (last) {                                // exactly one block gets here
        __threadfence();                       // acquire others' partials
        float s = 0.0f; int c = 0;
        for (int t = (int)threadIdx.x; t < GRID; t += BLK) {  // fixed order
            s += psum[t];
            c += pcnt[t];
        }
        for (int off = 32; off > 0; off >>= 1) {
            s += __shfl_down(s, off, 64);
            c += __shfl_down(c, off, 64);
        }
        if (lane == 0) { wsum[wid] = s; wcnt[wid] = c; }
        __syncthreads();
        if (threadIdx.x == 0) {
            float S = wsum[0] + wsum[1] + wsum[2] + wsum[3];
            int   C = wcnt[0] + wcnt[1] + wcnt[2] + wcnt[3];
            out[0] = S / (float)(C > 0 ? C : 1);
        }
    }
}

extern "C" void kernel_launch(void* const* d_in, const int* in_sizes, int n_in,
                              void* d_out, int out_size, void* d_ws, size_t ws_size,
                              hipStream_t stream) {
    const float* logit = (const float*)d_in[0];   // (N,1) f32
    const float* st    = (const float*)d_in[1];   // (N,2) f32

    float*        psum    = (float*)d_ws;                      // [GRID]
    int*          pcnt    = (int*)((char*)d_ws + GRID * 4);    // [GRID]
    unsigned int* counter = (unsigned int*)((char*)d_ws + GRID * 8);

    hipMemsetAsync(counter, 0, sizeof(unsigned int), stream);  // graph-safe
    svm_fused<<<GRID, BLK, 0, stream>>>(logit, st, psum, pcnt, counter,
                                        (float*)d_out);
}

// Round 3
// 39.690 us; speedup vs baseline: 1.2532x; 1.2532x over previous
//
#include <hip/hip_runtime.h>

// SvmLoss N=8192, RANK_RATIO=1.0 -> out = rank_loss (scalar f32).
// rank_loss = sum_{i,j} [t_i<t_j && status_i==1] * max(1+logit_j-logit_i,0)^2
//             / max(#pairs,1)
//
// R3: branch-free inner loop. Lane owns R=4 columns j (logit_j, time_j in
// VGPRs). i-chunk staged in LDS as (1-logit_i, t_eff_i) where t_eff = time if
// status==1 else 1e30 (kills both count and sum without any status logic in
// the loop). Inner loop: 1 wave-uniform ds_read_b64 broadcast + ~20 VALU per
// 256 pairs; count via ballot+popc on the SALU pipe (cnt stays in SGPR).

constexpr int N_   = 8192;
constexpr int BLK  = 256;
constexpr int R    = 4;               // j columns per lane
constexpr int JPB  = BLK * R;         // 1024 j per block
constexpr int NJB  = N_ / JPB;        // 8 j-blocks
constexpr int ICH  = 64;              // i per chunk
constexpr int NIC  = N_ / ICH;        // 128 i-chunks
constexpr int GRID = NJB * NIC;       // 1024 blocks = 4/CU

__global__ __launch_bounds__(BLK) void svm_fused(
        const float* __restrict__ logit,
        const float* __restrict__ st,      // [N][2] status,time
        float* __restrict__ psum,
        int*   __restrict__ pcnt,
        unsigned int* __restrict__ counter,
        float* __restrict__ out) {
    __shared__ float2 ci_s[ICH];          // (1 - logit_i, t_eff_i)

    const int jb = blockIdx.x & (NJB - 1);
    const int ic = blockIdx.x / NJB;
    const int j0 = jb * JPB + (int)threadIdx.x * R;   // 16B-aligned

    const float4 lj4 = *(const float4*)(logit + j0);
    const float4 sa  = *(const float4*)(st + 2 * j0);      // (s,t) j0,j0+1
    const float4 sb  = *(const float4*)(st + 2 * j0 + 4);  // (s,t) j0+2,j0+3
    const float lj0 = lj4.x, lj1 = lj4.y, lj2 = lj4.z, lj3 = lj4.w;
    const float tj0 = sa.y,  tj1 = sa.w,  tj2 = sb.y,  tj3 = sb.w;

    const int i0 = ic * ICH;
    if (threadIdx.x < ICH) {
        const int    i   = i0 + (int)threadIdx.x;
        const float  li  = logit[i];
        const float2 sv  = *(const float2*)(st + 2 * i);
        const float  te  = (sv.x == 1.0f) ? sv.y : 1e30f;  // status gate
        ci_s[threadIdx.x] = make_float2(1.0f - li, te);
    }
    __syncthreads();

    float s0 = 0.f, s1 = 0.f, s2 = 0.f, s3 = 0.f;
    int cnt = 0;                          // wave-uniform -> SGPR
    #pragma unroll 8
    for (int k = 0; k < ICH; ++k) {
        const float2 ct = ci_s[k];        // ds_read_b64 broadcast
        const float  c  = ct.x, te = ct.y;
        const bool m0 = te < tj0;
        const bool m1 = te < tj1;
        const bool m2 = te < tj2;
        const bool m3 = te < tj3;
        float h0 = fmaxf(c + lj0, 0.f); h0 = m0 ? h0 : 0.f; s0 = fmaf(h0, h0, s0);
        float h1 = fmaxf(c + lj1, 0.f); h1 = m1 ? h1 : 0.f; s1 = fmaf(h1, h1, s1);
        float h2 = fmaxf(c + lj2, 0.f); h2 = m2 ? h2 : 0.f; s2 = fmaf(h2, h2, s2);
        float h3 = fmaxf(c + lj3, 0.f); h3 = m3 ? h3 : 0.f; s3 = fmaf(h3, h3, s3);
        cnt += (int)__popcll(__ballot(m0));
        cnt += (int)__popcll(__ballot(m1));
        cnt += (int)__popcll(__ballot(m2));
        cnt += (int)__popcll(__ballot(m3));
    }

    // Wave reduce the float sum (cnt already wave-uniform)
    float sum = (s0 + s1) + (s2 + s3);
    for (int off = 32; off > 0; off >>= 1)
        sum += __shfl_down(sum, off, 64);

    __shared__ float wsum[BLK / 64];
    __shared__ int   wcnt[BLK / 64];
    __shared__ bool  last;
    const int lane = threadIdx.x & 63;
    const int wid  = threadIdx.x >> 6;
    if (lane == 0) { wsum[wid] = sum; wcnt[wid] = cnt; }
    __syncthreads();
    if (threadIdx.x == 0) {
        const float s = (wsum[0] + wsum[1]) + (wsum[2] + wsum[3]);
        const int   c =  wcnt[0] + wcnt[1] + wcnt[2] + wcnt[3];
        psum[blockIdx.x] = s;
        pcnt[blockIdx.x] = c;
        __threadfence();                        // release partials
        const unsigned int old = atomicAdd(counter, 1u);
        last = (old == GRID - 1);
    }
    __syncthreads();

    if (last) {                                 // exactly one block
        __threadfence();                        // acquire partials
        float s = 0.f; int c = 0;
        for (int t = (int)threadIdx.x; t < GRID; t += BLK) {  // fixed order
            s += psum[t];
            c += pcnt[t];
        }
        for (int off = 32; off > 0; off >>= 1) {
            s += __shfl_down(s, off, 64);
            c += __shfl_down(c, off, 64);
        }
        if (lane == 0) { wsum[wid] = s; wcnt[wid] = c; }
        __syncthreads();
        if (threadIdx.x == 0) {
            const float S = (wsum[0] + wsum[1]) + (wsum[2] + wsum[3]);
            const int   C =  wcnt[0] + wcnt[1] + wcnt[2] + wcnt[3];
            out[0] = S / (float)(C > 0 ? C : 1);
        }
    }
}

extern "C" void kernel_launch(void* const* d_in, const int* in_sizes, int n_in,
                              void* d_out, int out_size, void* d_ws, size_t ws_size,
                              hipStream_t stream) {
    const float* logit = (const float*)d_in[0];   // (N,1) f32
    const float* st    = (const float*)d_in[1];   // (N,2) f32

    float*        psum    = (float*)d_ws;                      // [GRID]
    int*          pcnt    = (int*)((char*)d_ws + GRID * 4);    // [GRID]
    unsigned int* counter = (unsigned int*)((char*)d_ws + GRID * 8);

    hipMemsetAsync(counter, 0, sizeof(unsigned int), stream);  // graph-safe
    svm_fused<<<GRID, BLK, 0, stream>>>(logit, st, psum, pcnt, counter,
                                        (float*)d_out);
}

// Round 4
// 18.736 us; speedup vs baseline: 2.6548x; 2.1184x over previous
//
#include <hip/hip_runtime.h>

// SvmLoss N=8192, RANK_RATIO=1.0 -> out = rank_loss (scalar f32).
// rank_loss = sum_{i,j} [t_i<t_j && status_i==1] * max(1+logit_j-logit_i,0)^2
//             / max(#pairs,1)
//
// R4: R3's branch-free register-resident inner loop (lane owns 4 j-columns;
// i-chunk broadcast from LDS; status folded into t_eff = status==1 ? t : 1e30)
// + R1's two-kernel deterministic reduction. The R2/R3 fused tail
// (__threadfence + same-address atomicAdd x1024 blocks) was the ~30 us cost:
// device fences force L2 writebacks and single-address atomics serialize at
// the coherence point. Kernel boundary = free global sync.

constexpr int N_   = 8192;
constexpr int BLK  = 256;
constexpr int R    = 4;               // j columns per lane
constexpr int JPB  = BLK * R;         // 1024 j per block
constexpr int NJB  = N_ / JPB;        // 8 j-blocks
constexpr int ICH  = 64;              // i per chunk
constexpr int NIC  = N_ / ICH;        // 128 i-chunks
constexpr int GRID = NJB * NIC;       // 1024 blocks = 4/CU, 4 waves/SIMD

__global__ __launch_bounds__(BLK) void svm_partial(
        const float* __restrict__ logit,
        const float* __restrict__ st,      // [N][2] status,time
        float* __restrict__ psum,
        int*   __restrict__ pcnt) {
    __shared__ float2 ci_s[ICH];          // (1 - logit_i, t_eff_i)

    const int jb = blockIdx.x & (NJB - 1);
    const int ic = blockIdx.x / NJB;
    const int j0 = jb * JPB + (int)threadIdx.x * R;   // 16B-aligned

    const float4 lj4 = *(const float4*)(logit + j0);
    const float4 sa  = *(const float4*)(st + 2 * j0);      // (s,t) j0,j0+1
    const float4 sb  = *(const float4*)(st + 2 * j0 + 4);  // (s,t) j0+2,j0+3
    const float lj0 = lj4.x, lj1 = lj4.y, lj2 = lj4.z, lj3 = lj4.w;
    const float tj0 = sa.y,  tj1 = sa.w,  tj2 = sb.y,  tj3 = sb.w;

    const int i0 = ic * ICH;
    if (threadIdx.x < ICH) {
        const int    i  = i0 + (int)threadIdx.x;
        const float  li = logit[i];
        const float2 sv = *(const float2*)(st + 2 * i);
        const float  te = (sv.x == 1.0f) ? sv.y : 1e30f;   // status gate
        ci_s[threadIdx.x] = make_float2(1.0f - li, te);
    }
    __syncthreads();

    float s0 = 0.f, s1 = 0.f, s2 = 0.f, s3 = 0.f;
    int cnt = 0;                          // wave-uniform -> SGPR
    #pragma unroll 8
    for (int k = 0; k < ICH; ++k) {
        const float2 ct = ci_s[k];        // ds_read_b64 broadcast
        const float  c  = ct.x, te = ct.y;
        const bool m0 = te < tj0;
        const bool m1 = te < tj1;
        const bool m2 = te < tj2;
        const bool m3 = te < tj3;
        float h0 = fmaxf(c + lj0, 0.f); h0 = m0 ? h0 : 0.f; s0 = fmaf(h0, h0, s0);
        float h1 = fmaxf(c + lj1, 0.f); h1 = m1 ? h1 : 0.f; s1 = fmaf(h1, h1, s1);
        float h2 = fmaxf(c + lj2, 0.f); h2 = m2 ? h2 : 0.f; s2 = fmaf(h2, h2, s2);
        float h3 = fmaxf(c + lj3, 0.f); h3 = m3 ? h3 : 0.f; s3 = fmaf(h3, h3, s3);
        cnt += (int)__popcll(__ballot(m0));
        cnt += (int)__popcll(__ballot(m1));
        cnt += (int)__popcll(__ballot(m2));
        cnt += (int)__popcll(__ballot(m3));
    }

    float sum = (s0 + s1) + (s2 + s3);
    for (int off = 32; off > 0; off >>= 1)
        sum += __shfl_down(sum, off, 64);

    __shared__ float wsum[BLK / 64];
    __shared__ int   wcnt[BLK / 64];
    const int lane = threadIdx.x & 63;
    const int wid  = threadIdx.x >> 6;
    if (lane == 0) { wsum[wid] = sum; wcnt[wid] = cnt; }
    __syncthreads();
    if (threadIdx.x == 0) {
        psum[blockIdx.x] = (wsum[0] + wsum[1]) + (wsum[2] + wsum[3]);
        pcnt[blockIdx.x] =  wcnt[0] + wcnt[1] + wcnt[2] + wcnt[3];
    }
}

__global__ __launch_bounds__(BLK) void svm_final(
        const float* __restrict__ psum,
        const int* __restrict__ pcnt,
        float* __restrict__ out) {
    float s = 0.f;
    int   c = 0;
    for (int t = (int)threadIdx.x; t < GRID; t += BLK) {   // fixed order
        s += psum[t];
        c += pcnt[t];
    }
    for (int off = 32; off > 0; off >>= 1) {
        s += __shfl_down(s, off, 64);
        c += __shfl_down(c, off, 64);
    }
    __shared__ float wsum[BLK / 64];
    __shared__ int   wcnt[BLK / 64];
    const int lane = threadIdx.x & 63;
    const int wid  = threadIdx.x >> 6;
    if (lane == 0) { wsum[wid] = s; wcnt[wid] = c; }
    __syncthreads();
    if (threadIdx.x == 0) {
        const float S = (wsum[0] + wsum[1]) + (wsum[2] + wsum[3]);
        const int   C =  wcnt[0] + wcnt[1] + wcnt[2] + wcnt[3];
        out[0] = S / (float)(C > 0 ? C : 1);
    }
}

extern "C" void kernel_launch(void* const* d_in, const int* in_sizes, int n_in,
                              void* d_out, int out_size, void* d_ws, size_t ws_size,
                              hipStream_t stream) {
    const float* logit = (const float*)d_in[0];   // (N,1) f32
    const float* st    = (const float*)d_in[1];   // (N,2) f32

    float* psum = (float*)d_ws;                      // [GRID]
    int*   pcnt = (int*)((char*)d_ws + GRID * 4);    // [GRID]

    svm_partial<<<GRID, BLK, 0, stream>>>(logit, st, psum, pcnt);
    svm_final<<<1, BLK, 0, stream>>>(psum, pcnt, (float*)d_out);
}